// Round 10
// baseline (57.384 us; speedup 1.0000x reference)
//
#include <hip/hip_runtime.h>
#include <hip/hip_bf16.h>
#include <math.h>

// Problem constants (fixed by setup_inputs)
static constexpr int Cc   = 16;   // C
static constexpr int COc  = 16;   // CO
static constexpr int Hh   = 4;    // heads
static constexpr int CPWc = 32;   // 2*C
static constexpr int NTH  = 256;  // block size

typedef __attribute__((ext_vector_type(8))) short bf16x8;   // 8 bf16 = 4 VGPR
typedef __attribute__((ext_vector_type(4))) float f32x4v;   // MFMA C/D

union F4 { float4 v; float f[4]; };

__device__ __forceinline__ short f2bf(float x) {
  __hip_bfloat16 h = __float2bfloat16(x);
  return *reinterpret_cast<short*>(&h);
}

// ---------------------------------------------------------------------------
// Kernel 1: per-row first-layer projections (validated r1-r9) + weight
// packing folded in (block nRowBlocks).
//   Pack layout (mfma_f32_16x16x32_bf16 B): lane l holds
//   B[k=(l>>4)*8+i][n=l&15], i=0..7.
//   w2f: K=32 x N=4 (cols>=4 zero).
//   v2f: BOTH K-halves hold v2*0.5 (k and k+16 -> same row): the val
//   A-fragment duplicates hv into both halves (branchless), so
//   D = sum_j hv[j&15] * 0.5*v2[j&15][n] * 2 = hv @ v2 exactly.
// ---------------------------------------------------------------------------
__global__ __launch_bounds__(NTH) void ppa_precompute(
    const float* __restrict__ xq, const float* __restrict__ xk,
    const float* __restrict__ w1, const float* __restrict__ b1,
    const float* __restrict__ v1, const float* __restrict__ bv1,
    const float* __restrict__ w2, const float* __restrict__ v2,
    float* __restrict__ aW, float* __restrict__ aV,
    float* __restrict__ cW, float* __restrict__ cV,
    ushort* __restrict__ w2f, ushort* __restrict__ v2f,
    int BN, int BK, int nRowBlocks) {
  const int t = threadIdx.x;

  if (blockIdx.x == nRowBlocks) {  // packing block
    if (t < 64) {
      const int n = t & 15, g = t >> 4;
#pragma unroll
      for (int i = 0; i < 8; ++i) {
        const int k = g * 8 + i;
        w2f[t * 8 + i] = (n < Hh) ? (ushort)f2bf(w2[k * Hh + n]) : (ushort)0;
        v2f[t * 8 + i] = (ushort)f2bf(0.5f * v2[(k & 15) * COc + n]);
      }
    }
    return;
  }

  __shared__ float sw1[CPWc * CPWc];
  __shared__ float sv1[CPWc * COc];
  __shared__ float sb1[CPWc];
  __shared__ float sbv1[COc];
  for (int i = t; i < CPWc * CPWc; i += NTH) sw1[i] = w1[i];
  for (int i = t; i < CPWc * COc; i += NTH) sv1[i] = v1[i];
  if (t < CPWc) sb1[t] = b1[t];
  if (t < COc) sbv1[t] = bv1[t];
  __syncthreads();

  const int r = blockIdx.x * NTH + t;
  if (r >= BN + BK) return;
  const bool isQ = (r < BN);
  const int rr = isQ ? r : (r - BN);
  const float* src = isQ ? (xq + (size_t)rr * Cc) : (xk + (size_t)rr * Cc);

  float x[Cc];
#pragma unroll
  for (int i = 0; i < Cc; i += 4) {
    float4 v = *reinterpret_cast<const float4*>(src + i);
    x[i] = v.x; x[i + 1] = v.y; x[i + 2] = v.z; x[i + 3] = v.w;
  }

  if (isQ) {
#pragma unroll
    for (int j = 0; j < CPWc; ++j) {
      float acc = sb1[j];
#pragma unroll
      for (int i = 0; i < Cc; ++i)
        acc += x[i] * (sw1[i * CPWc + j] - sw1[(i + Cc) * CPWc + j]);
      aW[(size_t)rr * CPWc + j] = acc;
    }
#pragma unroll
    for (int j = 0; j < COc; ++j) {
      float acc = sbv1[j];
#pragma unroll
      for (int i = 0; i < Cc; ++i)
        acc += x[i] * (sv1[i * COc + j] - sv1[(i + Cc) * COc + j]);
      aV[(size_t)rr * COc + j] = acc;
    }
  } else {
#pragma unroll
    for (int j = 0; j < CPWc; ++j) {
      float acc = 0.f;
#pragma unroll
      for (int i = 0; i < Cc; ++i) acc += x[i] * sw1[(i + Cc) * CPWc + j];
      cW[(size_t)rr * CPWc + j] = acc;
    }
#pragma unroll
    for (int j = 0; j < COc; ++j) {
      float acc = 0.f;
#pragma unroll
      for (int i = 0; i < Cc; ++i) acc += x[i] * sv1[(i + Cc) * COc + j];
      cV[(size_t)rr * COc + j] = acc;
    }
  }
}

// ---------------------------------------------------------------------------
// Kernel 2 (MFMA): one block per (b,n) row, 4 waves, each wave owns a 256-k
// quarter as 16 tiles of 16 k's.
// R10 changes vs r9 (whose main dispatch was latency-bound: VGPR stuck at
// 32 -> no cross-tile load overlap, 58% stall):
//   (a) explicit register double-buffer: tile s+1's 4 b128 loads issue
//       before tile s is processed (full static unroll, copies SSA'd away);
//   (b) branchless val path: all lanes build the hv fragment (lanes g>=2
//       duplicate g&1's octet; v2f holds 0.5*v2 in both K-halves);
//   (c) biases folded into MFMA C operand (C/D col=lane&15 -> bias is
//       per-lane constant b2[m] / bv2[m] across all 4 D regs).
// Softmax plain exp-sum (logits ReLU'd >= 0; validated r1-r9). p routed
// head-lanes -> all lanes via __shfl (psrc = (lane&48)|(m>>2)).
// l-accum on lanes m&3==0 (each (h,k-quad) counted once; validated r9).
// No launch-bounds cap (r2-r7 law: cap = 256/w -> scratch spill).
// ---------------------------------------------------------------------------
__global__ __launch_bounds__(NTH) void ppa_main_mfma(
    const float* __restrict__ aW, const float* __restrict__ aV,
    const float* __restrict__ cW, const float* __restrict__ cV,
    const ushort* __restrict__ w2f, const float* __restrict__ b2,
    const ushort* __restrict__ v2f, const float* __restrict__ bv2,
    float* __restrict__ out, int N, int Nk) {
  __shared__ float sro[4][COc];
  __shared__ float srl[4][Hh];

  const int t = threadIdx.x;
  const int lane = t & 63, w = t >> 6;
  const int m = lane & 15;   // A-row in tile; output col c; head col h
  const int g = lane >> 4;   // k-octet group (cW); g&1 for cV
  const int gg = g & 1;
  const int hh = m >> 2;     // head for this output col
  const int psrc = (lane & 48) | hh;  // lane holding p[.][hh] in this g-group
  const int row = blockIdx.x;
  const int b = row / N;

  // Loop-invariant per-lane data.
  float a_reg[8];
  {
    const float* aRow = aW + (size_t)row * CPWc + g * 8;
#pragma unroll
    for (int i = 0; i < 8; i += 4) {
      F4 v; v.v = *reinterpret_cast<const float4*>(aRow + i);
      a_reg[i] = v.f[0]; a_reg[i + 1] = v.f[1];
      a_reg[i + 2] = v.f[2]; a_reg[i + 3] = v.f[3];
    }
  }
  float av_reg[8];
  {
    const float* avRow = aV + (size_t)row * COc + gg * 8;
#pragma unroll
    for (int i = 0; i < 8; i += 4) {
      F4 v; v.v = *reinterpret_cast<const float4*>(avRow + i);
      av_reg[i] = v.f[0]; av_reg[i + 1] = v.f[1];
      av_reg[i + 2] = v.f[2]; av_reg[i + 3] = v.f[3];
    }
  }
  const bf16x8 wfrag = *reinterpret_cast<const bf16x8*>(w2f + lane * 8);
  const bf16x8 vfrag = *reinterpret_cast<const bf16x8*>(v2f + lane * 8);
  const float b2h = b2[m < Hh ? m : (Hh - 1)];
  const float bv2c = bv2[m];
  const f32x4v cbW = {b2h, b2h, b2h, b2h};
  const f32x4v cbV = {bv2c, bv2c, bv2c, bv2c};

  float o_acc = 0.f, l_acc = 0.f;

  const float* cWb = cW + (size_t)b * Nk * CPWc;
  const float* cVb = cV + (size_t)b * Nk * COc;

  const int kPerWave = Nk / 4;        // 256
  const int base0 = w * kPerWave;
  const int nTiles = kPerWave / 16;   // 16

  // ---- software pipeline: prefetch tile s+1 while processing tile s.
  F4 c0, c1, d0, d1;
  {
    const size_t km = (size_t)(base0 + m);
    const float* pw = cWb + km * CPWc + g * 8;
    const float* pv = cVb + km * COc + gg * 8;
    c0.v = *reinterpret_cast<const float4*>(pw);
    c1.v = *reinterpret_cast<const float4*>(pw + 4);
    d0.v = *reinterpret_cast<const float4*>(pv);
    d1.v = *reinterpret_cast<const float4*>(pv + 4);
  }

#pragma unroll
  for (int s = 0; s < 16; ++s) {
    F4 n0 = {}, n1 = {}, e0 = {}, e1 = {};
    if (s < 15) {
      const size_t km = (size_t)(base0 + (s + 1) * 16 + m);
      const float* pw = cWb + km * CPWc + g * 8;
      const float* pv = cVb + km * COc + gg * 8;
      n0.v = *reinterpret_cast<const float4*>(pw);
      n1.v = *reinterpret_cast<const float4*>(pw + 4);
      e0.v = *reinterpret_cast<const float4*>(pv);
      e1.v = *reinterpret_cast<const float4*>(pv + 4);
    }

    // ---- logits tile: A = hw = relu(a + cW)[m][g*8..g*8+7]; C = b2.
    const bf16x8 afW = {
      f2bf(fmaxf(a_reg[0] + c0.f[0], 0.f)),
      f2bf(fmaxf(a_reg[1] + c0.f[1], 0.f)),
      f2bf(fmaxf(a_reg[2] + c0.f[2], 0.f)),
      f2bf(fmaxf(a_reg[3] + c0.f[3], 0.f)),
      f2bf(fmaxf(a_reg[4] + c1.f[0], 0.f)),
      f2bf(fmaxf(a_reg[5] + c1.f[1], 0.f)),
      f2bf(fmaxf(a_reg[6] + c1.f[2], 0.f)),
      f2bf(fmaxf(a_reg[7] + c1.f[3], 0.f)),
    };
    const f32x4v lgD =
        __builtin_amdgcn_mfma_f32_16x16x32_bf16(afW, wfrag, cbW, 0, 0, 0);

    // p on head-lanes (col h = m < 4); rows k_local = g*4 + r.
    const float p0 = __expf(fmaxf(lgD[0], 0.f));
    const float p1 = __expf(fmaxf(lgD[1], 0.f));
    const float p2 = __expf(fmaxf(lgD[2], 0.f));
    const float p3 = __expf(fmaxf(lgD[3], 0.f));

    // Route p to all lanes of the g-group.
    const float q0 = __shfl(p0, psrc);
    const float q1 = __shfl(p1, psrc);
    const float q2 = __shfl(p2, psrc);
    const float q3 = __shfl(p3, psrc);
    if ((m & 3) == 0) l_acc += (q0 + q1) + (q2 + q3);

    // ---- val tile: A = hv duplicated into both K-halves; B = 0.5*v2 dup;
    //      C = bv2. Branchless: all 64 lanes identical work.
    const bf16x8 afV = {
      f2bf(fmaxf(av_reg[0] + d0.f[0], 0.f)),
      f2bf(fmaxf(av_reg[1] + d0.f[1], 0.f)),
      f2bf(fmaxf(av_reg[2] + d0.f[2], 0.f)),
      f2bf(fmaxf(av_reg[3] + d0.f[3], 0.f)),
      f2bf(fmaxf(av_reg[4] + d1.f[0], 0.f)),
      f2bf(fmaxf(av_reg[5] + d1.f[1], 0.f)),
      f2bf(fmaxf(av_reg[6] + d1.f[2], 0.f)),
      f2bf(fmaxf(av_reg[7] + d1.f[3], 0.f)),
    };
    const f32x4v vD =
        __builtin_amdgcn_mfma_f32_16x16x32_bf16(afV, vfrag, cbV, 0, 0, 0);

    o_acc += q0 * fmaxf(vD[0], 0.f);
    o_acc += q1 * fmaxf(vD[1], 0.f);
    o_acc += q2 * fmaxf(vD[2], 0.f);
    o_acc += q3 * fmaxf(vD[3], 0.f);

    c0 = n0; c1 = n1; d0 = e0; d1 = e1;
  }

  // ---- reduce over g-groups (xor 16/32 preserves m), then across waves.
  o_acc += __shfl_xor(o_acc, 16);
  o_acc += __shfl_xor(o_acc, 32);
  l_acc += __shfl_xor(l_acc, 16);
  l_acc += __shfl_xor(l_acc, 32);
  if (lane < COc) sro[w][m] = o_acc;
  if (lane < COc && (lane & 3) == 0) srl[w][lane >> 2] = l_acc;
  __syncthreads();

  if (t < COc) {
    const float osum = (sro[0][t] + sro[1][t]) + (sro[2][t] + sro[3][t]);
    const int h = t >> 2;
    const float lsum = (srl[0][h] + srl[1][h]) + (srl[2][h] + srl[3][h]);
    out[(size_t)row * COc + t] = osum / lsum;
  }
}

// ---------------------------------------------------------------------------
extern "C" void kernel_launch(void* const* d_in, const int* in_sizes, int n_in,
                              void* d_out, int out_size, void* d_ws, size_t ws_size,
                              hipStream_t stream) {
  const float* xq  = (const float*)d_in[0];
  const float* xk  = (const float*)d_in[1];
  const float* w1  = (const float*)d_in[2];
  const float* b1  = (const float*)d_in[3];
  const float* w2  = (const float*)d_in[4];
  const float* b2  = (const float*)d_in[5];
  const float* v1  = (const float*)d_in[6];
  const float* bv1 = (const float*)d_in[7];
  const float* v2  = (const float*)d_in[8];
  const float* bv2 = (const float*)d_in[9];
  float* out = (float*)d_out;

  const int BN = in_sizes[0] / Cc;  // B*N  = 2048
  const int BK = in_sizes[1] / Cc;  // B*Nk = 2048
  const int B = 2;                  // fixed by setup_inputs
  const int N = BN / B;
  const int Nk = BK / B;

  float* ws = (float*)d_ws;
  float* aW = ws;                          // BN*32
  float* aV = aW + (size_t)BN * CPWc;      // BN*16
  float* cW = aV + (size_t)BN * COc;       // BK*32
  float* cV = cW + (size_t)BK * CPWc;      // BK*16
  ushort* w2f = (ushort*)(cV + (size_t)BK * COc);  // 64*8 ushort
  ushort* v2f = w2f + 64 * 8;                      // 64*8 ushort

  const int totalRows = BN + BK;
  const int pgrid = (totalRows + NTH - 1) / NTH;
  ppa_precompute<<<pgrid + 1, NTH, 0, stream>>>(
      xq, xk, w1, b1, v1, bv1, w2, v2,
      aW, aV, cW, cV, w2f, v2f, BN, BK, pgrid);
  ppa_main_mfma<<<BN, NTH, 0, stream>>>(aW, aV, cW, cV, w2f, b2, v2f, bv2,
                                        out, N, Nk);
}

// Round 11
// 33.089 us; speedup vs baseline: 1.7343x; 1.7343x over previous
//
#include <hip/hip_runtime.h>
#include <hip/hip_bf16.h>
#include <math.h>

// Problem constants (fixed by setup_inputs)
static constexpr int Cc   = 16;   // C
static constexpr int COc  = 16;   // CO
static constexpr int Hh   = 4;    // heads
static constexpr int CPWc = 32;   // 2*C
static constexpr int NTH  = 256;  // block size
static constexpr int TFL  = 768;  // floats per packed 16-k tile (3 KB)

typedef __attribute__((ext_vector_type(8))) short bf16x8;   // 8 bf16 = 4 VGPR
typedef __attribute__((ext_vector_type(4))) float f32x4v;   // MFMA C/D

union F4 { float4 v; float f[4]; };

__device__ __forceinline__ short f2bf(float x) {
  __hip_bfloat16 h = __float2bfloat16(x);
  return *reinterpret_cast<short*>(&h);
}

// ---------------------------------------------------------------------------
// Kernel 1: per-row first-layer projections + packing.
// q rows -> aW/aV (linear, validated r1-r10).
// k rows -> cP, a CONSUMPTION-ORDERED packed layout: per 16-k tile T a
// 768-float block with four dense regions, so the main kernel's four b128
// loads are each `base + lane*16B` (fully coalesced, every line touched
// once -- r11 theory: the r8-r10 46us wall is L1/TA line throughput on the
// old scattered tile reads):
//   [  0,256): lane l=g*16+m -> cW[k=T*16+m][g*8 .. g*8+3]
//   [256,512): lane l        -> cW[k][g*8+4 .. g*8+7]
//   [512,640): lane l&31 (gg*16+m, gg=g&1) -> cV[k][gg*8 .. gg*8+3]
//   [640,768): lane l&31     -> cV[k][gg*8+4 .. gg*8+7]
// (cV regions are 32-lane; lanes 32-63 broadcast-read the same 16B.)
// Block nRowBlocks packs w2/v2 MFMA B-fragments (layout validated r8-r10;
// v2f holds 0.5*v2 in both K-halves, A duplicates hv -> exact).
// ---------------------------------------------------------------------------
__global__ __launch_bounds__(NTH) void ppa_precompute(
    const float* __restrict__ xq, const float* __restrict__ xk,
    const float* __restrict__ w1, const float* __restrict__ b1,
    const float* __restrict__ v1, const float* __restrict__ bv1,
    const float* __restrict__ w2, const float* __restrict__ v2,
    float* __restrict__ aW, float* __restrict__ aV,
    float* __restrict__ cP,
    ushort* __restrict__ w2f, ushort* __restrict__ v2f,
    int BN, int BK, int Nk, int nRowBlocks) {
  const int t = threadIdx.x;

  if (blockIdx.x == nRowBlocks) {  // packing block
    if (t < 64) {
      const int n = t & 15, g = t >> 4;
#pragma unroll
      for (int i = 0; i < 8; ++i) {
        const int k = g * 8 + i;
        w2f[t * 8 + i] = (n < Hh) ? (ushort)f2bf(w2[k * Hh + n]) : (ushort)0;
        v2f[t * 8 + i] = (ushort)f2bf(0.5f * v2[(k & 15) * COc + n]);
      }
    }
    return;
  }

  __shared__ float sw1[CPWc * CPWc];
  __shared__ float sv1[CPWc * COc];
  __shared__ float sb1[CPWc];
  __shared__ float sbv1[COc];
  for (int i = t; i < CPWc * CPWc; i += NTH) sw1[i] = w1[i];
  for (int i = t; i < CPWc * COc; i += NTH) sv1[i] = v1[i];
  if (t < CPWc) sb1[t] = b1[t];
  if (t < COc) sbv1[t] = bv1[t];
  __syncthreads();

  const int r = blockIdx.x * NTH + t;
  if (r >= BN + BK) return;
  const bool isQ = (r < BN);
  const int rr = isQ ? r : (r - BN);
  const float* src = isQ ? (xq + (size_t)rr * Cc) : (xk + (size_t)rr * Cc);

  float x[Cc];
#pragma unroll
  for (int i = 0; i < Cc; i += 4) {
    float4 v = *reinterpret_cast<const float4*>(src + i);
    x[i] = v.x; x[i + 1] = v.y; x[i + 2] = v.z; x[i + 3] = v.w;
  }

  if (isQ) {
#pragma unroll
    for (int j = 0; j < CPWc; ++j) {
      float acc = sb1[j];
#pragma unroll
      for (int i = 0; i < Cc; ++i)
        acc += x[i] * (sw1[i * CPWc + j] - sw1[(i + Cc) * CPWc + j]);
      aW[(size_t)rr * CPWc + j] = acc;
    }
#pragma unroll
    for (int j = 0; j < COc; ++j) {
      float acc = sbv1[j];
#pragma unroll
      for (int i = 0; i < Cc; ++i)
        acc += x[i] * (sv1[i * COc + j] - sv1[(i + Cc) * COc + j]);
      aV[(size_t)rr * COc + j] = acc;
    }
  } else {
    float cw[CPWc], cv[COc];
#pragma unroll
    for (int j = 0; j < CPWc; ++j) {
      float acc = 0.f;
#pragma unroll
      for (int i = 0; i < Cc; ++i) acc += x[i] * sw1[(i + Cc) * CPWc + j];
      cw[j] = acc;
    }
#pragma unroll
    for (int j = 0; j < COc; ++j) {
      float acc = 0.f;
#pragma unroll
      for (int i = 0; i < Cc; ++i) acc += x[i] * sv1[(i + Cc) * COc + j];
      cv[j] = acc;
    }
    const int bb = rr / Nk;
    const int kk = rr - bb * Nk;
    const int T = kk >> 4, mm = kk & 15;
    float* tp = cP + ((size_t)bb * (Nk >> 4) + T) * TFL;
#pragma unroll
    for (int g = 0; g < 4; ++g) {
      F4 w0, w1s;
#pragma unroll
      for (int i = 0; i < 4; ++i) { w0.f[i] = cw[g * 8 + i]; w1s.f[i] = cw[g * 8 + 4 + i]; }
      *reinterpret_cast<float4*>(tp + (g * 16 + mm) * 4) = w0.v;
      *reinterpret_cast<float4*>(tp + 256 + (g * 16 + mm) * 4) = w1s.v;
    }
#pragma unroll
    for (int gg = 0; gg < 2; ++gg) {
      F4 v0, v1s;
#pragma unroll
      for (int i = 0; i < 4; ++i) { v0.f[i] = cv[gg * 8 + i]; v1s.f[i] = cv[gg * 8 + 4 + i]; }
      *reinterpret_cast<float4*>(tp + 512 + (gg * 16 + mm) * 4) = v0.v;
      *reinterpret_cast<float4*>(tp + 640 + (gg * 16 + mm) * 4) = v1s.v;
    }
  }
}

// ---------------------------------------------------------------------------
// Kernel 2 (MFMA): one block per (b,n) row, 4 waves, wave w owns tiles
// T = w*16+s (16 k's each). All four per-tile loads are dense b128s from
// the packed cP block (lane*16B within each region). Software pipeline:
// tile s+1 loads issue before tile s's compute (full static unroll).
// Fragment math, p-shfl routing (psrc=(lane&48)|(m>>2)), bias-in-C, and
// l-accum on lanes m&3==0 all validated r8-r10. Plain exp-sum softmax
// (logits ReLU'd >= 0). No launch-bounds cap (r2-r7 law: cap -> spill).
// ---------------------------------------------------------------------------
__global__ __launch_bounds__(NTH) void ppa_main_mfma(
    const float* __restrict__ aW, const float* __restrict__ aV,
    const float* __restrict__ cP,
    const ushort* __restrict__ w2f, const float* __restrict__ b2,
    const ushort* __restrict__ v2f, const float* __restrict__ bv2,
    float* __restrict__ out, int N, int Nk) {
  __shared__ float sro[4][COc];
  __shared__ float srl[4][Hh];

  const int t = threadIdx.x;
  const int lane = t & 63, w = t >> 6;
  const int m = lane & 15;   // A-row in tile; output col c; head col h
  const int g = lane >> 4;   // k-octet group (cW); g&1 for cV
  const int gg = g & 1;
  const int l31 = lane & 31;
  const int hh = m >> 2;     // head for this output col
  const int psrc = (lane & 48) | hh;  // lane holding p[.][hh] in this g-group
  const int row = blockIdx.x;
  const int b = row / N;

  // Loop-invariant per-lane data.
  float a_reg[8];
  {
    const float* aRow = aW + (size_t)row * CPWc + g * 8;
#pragma unroll
    for (int i = 0; i < 8; i += 4) {
      F4 v; v.v = *reinterpret_cast<const float4*>(aRow + i);
      a_reg[i] = v.f[0]; a_reg[i + 1] = v.f[1];
      a_reg[i + 2] = v.f[2]; a_reg[i + 3] = v.f[3];
    }
  }
  float av_reg[8];
  {
    const float* avRow = aV + (size_t)row * COc + gg * 8;
#pragma unroll
    for (int i = 0; i < 8; i += 4) {
      F4 v; v.v = *reinterpret_cast<const float4*>(avRow + i);
      av_reg[i] = v.f[0]; av_reg[i + 1] = v.f[1];
      av_reg[i + 2] = v.f[2]; av_reg[i + 3] = v.f[3];
    }
  }
  const bf16x8 wfrag = *reinterpret_cast<const bf16x8*>(w2f + lane * 8);
  const bf16x8 vfrag = *reinterpret_cast<const bf16x8*>(v2f + lane * 8);
  const float b2h = b2[m < Hh ? m : (Hh - 1)];
  const float bv2c = bv2[m];
  const f32x4v cbW = {b2h, b2h, b2h, b2h};
  const f32x4v cbV = {bv2c, bv2c, bv2c, bv2c};

  float o_acc = 0.f, l_acc = 0.f;

  // Wave's packed tile base: tiles T = w*16 + s, block stride TFL floats.
  const float* tb = cP + ((size_t)b * (Nk >> 4) + (size_t)w * 16) * TFL;

  // ---- software pipeline: prefetch tile s+1 while processing tile s.
  F4 c0, c1, d0, d1;
  c0.v = *reinterpret_cast<const float4*>(tb + lane * 4);
  c1.v = *reinterpret_cast<const float4*>(tb + 256 + lane * 4);
  d0.v = *reinterpret_cast<const float4*>(tb + 512 + l31 * 4);
  d1.v = *reinterpret_cast<const float4*>(tb + 640 + l31 * 4);

#pragma unroll
  for (int s = 0; s < 16; ++s) {
    F4 n0 = {}, n1 = {}, e0 = {}, e1 = {};
    if (s < 15) {
      const float* nb = tb + (size_t)(s + 1) * TFL;
      n0.v = *reinterpret_cast<const float4*>(nb + lane * 4);
      n1.v = *reinterpret_cast<const float4*>(nb + 256 + lane * 4);
      e0.v = *reinterpret_cast<const float4*>(nb + 512 + l31 * 4);
      e1.v = *reinterpret_cast<const float4*>(nb + 640 + l31 * 4);
    }

    // ---- logits tile: A = hw = relu(a + cW)[m][g*8..g*8+7]; C = b2.
    const bf16x8 afW = {
      f2bf(fmaxf(a_reg[0] + c0.f[0], 0.f)),
      f2bf(fmaxf(a_reg[1] + c0.f[1], 0.f)),
      f2bf(fmaxf(a_reg[2] + c0.f[2], 0.f)),
      f2bf(fmaxf(a_reg[3] + c0.f[3], 0.f)),
      f2bf(fmaxf(a_reg[4] + c1.f[0], 0.f)),
      f2bf(fmaxf(a_reg[5] + c1.f[1], 0.f)),
      f2bf(fmaxf(a_reg[6] + c1.f[2], 0.f)),
      f2bf(fmaxf(a_reg[7] + c1.f[3], 0.f)),
    };
    const f32x4v lgD =
        __builtin_amdgcn_mfma_f32_16x16x32_bf16(afW, wfrag, cbW, 0, 0, 0);

    // p on head-lanes (col h = m < 4); rows k_local = g*4 + r.
    const float p0 = __expf(fmaxf(lgD[0], 0.f));
    const float p1 = __expf(fmaxf(lgD[1], 0.f));
    const float p2 = __expf(fmaxf(lgD[2], 0.f));
    const float p3 = __expf(fmaxf(lgD[3], 0.f));

    // Route p to all lanes of the g-group.
    const float q0 = __shfl(p0, psrc);
    const float q1 = __shfl(p1, psrc);
    const float q2 = __shfl(p2, psrc);
    const float q3 = __shfl(p3, psrc);
    if ((m & 3) == 0) l_acc += (q0 + q1) + (q2 + q3);

    // ---- val tile: A = hv duplicated into both K-halves (v2f = 0.5*v2 in
    //      both halves -> exact); C = bv2. Branchless, broadcast cV reads.
    const bf16x8 afV = {
      f2bf(fmaxf(av_reg[0] + d0.f[0], 0.f)),
      f2bf(fmaxf(av_reg[1] + d0.f[1], 0.f)),
      f2bf(fmaxf(av_reg[2] + d0.f[2], 0.f)),
      f2bf(fmaxf(av_reg[3] + d0.f[3], 0.f)),
      f2bf(fmaxf(av_reg[4] + d1.f[0], 0.f)),
      f2bf(fmaxf(av_reg[5] + d1.f[1], 0.f)),
      f2bf(fmaxf(av_reg[6] + d1.f[2], 0.f)),
      f2bf(fmaxf(av_reg[7] + d1.f[3], 0.f)),
    };
    const f32x4v vD =
        __builtin_amdgcn_mfma_f32_16x16x32_bf16(afV, vfrag, cbV, 0, 0, 0);

    o_acc += q0 * fmaxf(vD[0], 0.f);
    o_acc += q1 * fmaxf(vD[1], 0.f);
    o_acc += q2 * fmaxf(vD[2], 0.f);
    o_acc += q3 * fmaxf(vD[3], 0.f);

    c0 = n0; c1 = n1; d0 = e0; d1 = e1;
  }

  // ---- reduce over g-groups (xor 16/32 preserves m), then across waves.
  o_acc += __shfl_xor(o_acc, 16);
  o_acc += __shfl_xor(o_acc, 32);
  l_acc += __shfl_xor(l_acc, 16);
  l_acc += __shfl_xor(l_acc, 32);
  if (lane < COc) sro[w][m] = o_acc;
  if (lane < COc && (lane & 3) == 0) srl[w][lane >> 2] = l_acc;
  __syncthreads();

  if (t < COc) {
    const float osum = (sro[0][t] + sro[1][t]) + (sro[2][t] + sro[3][t]);
    const int h = t >> 2;
    const float lsum = (srl[0][h] + srl[1][h]) + (srl[2][h] + srl[3][h]);
    out[(size_t)row * COc + t] = osum / lsum;
  }
}

// ---------------------------------------------------------------------------
extern "C" void kernel_launch(void* const* d_in, const int* in_sizes, int n_in,
                              void* d_out, int out_size, void* d_ws, size_t ws_size,
                              hipStream_t stream) {
  const float* xq  = (const float*)d_in[0];
  const float* xk  = (const float*)d_in[1];
  const float* w1  = (const float*)d_in[2];
  const float* b1  = (const float*)d_in[3];
  const float* w2  = (const float*)d_in[4];
  const float* b2  = (const float*)d_in[5];
  const float* v1  = (const float*)d_in[6];
  const float* bv1 = (const float*)d_in[7];
  const float* v2  = (const float*)d_in[8];
  const float* bv2 = (const float*)d_in[9];
  float* out = (float*)d_out;

  const int BN = in_sizes[0] / Cc;  // B*N  = 2048
  const int BK = in_sizes[1] / Cc;  // B*Nk = 2048
  const int B = 2;                  // fixed by setup_inputs
  const int N = BN / B;
  const int Nk = BK / B;

  float* ws = (float*)d_ws;
  float* aW = ws;                              // BN*32
  float* aV = aW + (size_t)BN * CPWc;          // BN*16
  float* cP = aV + (size_t)BN * COc;           // BK*48 (packed tiles)
  ushort* w2f = (ushort*)(cP + (size_t)BK * 48);  // 64*8 ushort
  ushort* v2f = w2f + 64 * 8;                     // 64*8 ushort

  const int totalRows = BN + BK;
  const int pgrid = (totalRows + NTH - 1) / NTH;
  ppa_precompute<<<pgrid + 1, NTH, 0, stream>>>(
      xq, xk, w1, b1, v1, bv1, w2, v2,
      aW, aV, cP, w2f, v2f, BN, BK, Nk, pgrid);
  ppa_main_mfma<<<BN, NTH, 0, stream>>>(aW, aV, cP, w2f, b2, v2f, bv2,
                                        out, N, Nk);
}